// Round 14
// baseline (36.493 us; speedup 1.0000x reference)
//
#include <hip/hip_runtime.h>
#include <hip/hip_bf16.h>

typedef __attribute__((ext_vector_type(8))) short short8;
typedef __attribute__((ext_vector_type(4))) float f32x4;

#define LOG2E 1.4426950408889634f

__device__ __forceinline__ float bf2f(unsigned short s) {
    return __uint_as_float((unsigned int)s << 16);
}
__device__ __forceinline__ float fast_exp2(float x) {
#if __has_builtin(__builtin_amdgcn_exp2f)
    return __builtin_amdgcn_exp2f(x);
#else
    return __expf(x * 0.6931471805599453f);
#endif
}
__device__ __forceinline__ unsigned int cvt_pk_bf16(float lo, float hi) {
    unsigned int r;
    asm("v_cvt_pk_bf16_f32 %0, %1, %2" : "=v"(r) : "v"(lo), "v"(hi));
    return r;
}

// ---------------------------------------------------------------------------
// Kernel 1: MFMA 1x1-conv projections + 2x2 maxpool (R6 verbatim, proven).
// ---------------------------------------------------------------------------
__global__ __launch_bounds__(256, 2) void proj_pool_kernel(
    const float* __restrict__ x, const float* __restrict__ Wq,
    const float* __restrict__ Wk, const float* __restrict__ Wv,
    unsigned short* __restrict__ q_ws, unsigned short* __restrict__ k_ws,
    unsigned short* __restrict__ v_t)
{
    __shared__ __align__(16) char smem[28672];
    char* xT = smem;                                    // [128 n][128 B] bf16, swizzled
    unsigned int* kv = (unsigned int*)(smem + 16384);   // [128 n][24 u32] (40 bf16 ch)

    const int b = blockIdx.x >> 5, s = blockIdx.x & 31;
    const int n0 = s * 128;
    const int t = threadIdx.x;
    const int w = t >> 6, lane = t & 63;
    const int l16 = lane & 15, g4 = lane >> 4;

    short8 wf[3][2];
#pragma unroll
    for (int tile = 0; tile < 3; ++tile) {
        const float* wrow;
        float scale = 1.0f;
        if (tile == 0) {
            if (l16 < 8) { wrow = Wq + l16 * 64; scale = LOG2E * 0.25f; }
            else         { wrow = Wk + (l16 - 8) * 64; }
        } else if (tile == 1) wrow = Wv + l16 * 64;
        else                  wrow = Wv + (16 + l16) * 64;
#pragma unroll
        for (int ks = 0; ks < 2; ++ks) {
            const float4 wa = *(const float4*)(wrow + ks * 32 + g4 * 8);
            const float4 wb = *(const float4*)(wrow + ks * 32 + g4 * 8 + 4);
            union { unsigned int u[4]; short8 s8; } uu;
            uu.u[0] = cvt_pk_bf16(wa.x * scale, wa.y * scale);
            uu.u[1] = cvt_pk_bf16(wa.z * scale, wa.w * scale);
            uu.u[2] = cvt_pk_bf16(wb.x * scale, wb.y * scale);
            uu.u[3] = cvt_pk_bf16(wb.z * scale, wb.w * scale);
            wf[tile][ks] = uu.s8;
        }
    }

    {
        const int nloc = (w & 1) * 64 + lane;      // 0..127
        const int cbase = (w >> 1) * 32;
        const float* xp = x + (size_t)b * 262144 + (size_t)cbase * 4096 + n0 + nloc;
        unsigned int pk[16];
#pragma unroll
        for (int j = 0; j < 16; ++j) {
            const float e0 = xp[(size_t)(2 * j) * 4096];
            const float e1 = xp[(size_t)(2 * j + 1) * 4096];
            pk[j] = cvt_pk_bf16(e0, e1);
        }
        char* row = xT + nloc * 128;
        const int sw = (nloc & 7) << 4;
#pragma unroll
        for (int h = 0; h < 4; ++h) {
            const uint4 u = make_uint4(pk[h*4+0], pk[h*4+1], pk[h*4+2], pk[h*4+3]);
            *(uint4*)(row + ((((cbase >> 3) + h) * 16) ^ sw)) = u;
        }
    }
    __syncthreads();

#pragma unroll
    for (int p = 0; p < 2; ++p) {
        const int tile = w * 2 + p;
        const int nl = tile * 16 + l16;
        f32x4 C0 = {0,0,0,0}, C1 = {0,0,0,0}, C2 = {0,0,0,0};
#pragma unroll
        for (int ks = 0; ks < 2; ++ks) {
            const short8 xb = *(const short8*)(xT + nl * 128 + ((((ks*4+g4)*16)) ^ ((l16&7)<<4)));
            C0 = __builtin_amdgcn_mfma_f32_16x16x32_bf16(wf[0][ks], xb, C0, 0, 0, 0);
            C1 = __builtin_amdgcn_mfma_f32_16x16x32_bf16(wf[1][ks], xb, C1, 0, 0, 0);
            C2 = __builtin_amdgcn_mfma_f32_16x16x32_bf16(wf[2][ks], xb, C2, 0, 0, 0);
        }
        const unsigned int c0lo = cvt_pk_bf16(C0[0], C0[1]);
        const unsigned int c0hi = cvt_pk_bf16(C0[2], C0[3]);
        if (g4 < 2) {
            *(uint2*)(q_ws + (size_t)(b * 4096 + n0 + nl) * 8 + g4 * 4) = make_uint2(c0lo, c0hi);
        } else {
            *(uint2*)&kv[nl * 24 + (g4 - 2) * 2] = make_uint2(c0lo, c0hi);
        }
        *(uint2*)&kv[nl * 24 + 4 + g4 * 2] =
            make_uint2(cvt_pk_bf16(C1[0], C1[1]), cvt_pk_bf16(C1[2], C1[3]));
        *(uint2*)&kv[nl * 24 + 12 + g4 * 2] =
            make_uint2(cvt_pk_bf16(C2[0], C2[1]), cvt_pk_bf16(C2[2], C2[3]));
    }
    __syncthreads();

    if (t < 128) {
        const int m = t >> 2, cg = t & 3;
        const int r0 = m * 2, r2 = m * 2 + 64;
        const int mg = s * 32 + m;
        unsigned int res[5];
#pragma unroll
        for (int i = 0; i < 5; ++i) {
            const unsigned int a  = kv[(r0    ) * 24 + cg * 5 + i];
            const unsigned int b1 = kv[(r0 + 1) * 24 + cg * 5 + i];
            const unsigned int c  = kv[(r2    ) * 24 + cg * 5 + i];
            const unsigned int d  = kv[(r2 + 1) * 24 + cg * 5 + i];
            const float lo = fmaxf(fmaxf(bf2f(a & 0xffff), bf2f(b1 & 0xffff)),
                                   fmaxf(bf2f(c & 0xffff), bf2f(d & 0xffff)));
            const float hi = fmaxf(fmaxf(bf2f(a >> 16), bf2f(b1 >> 16)),
                                   fmaxf(bf2f(c >> 16), bf2f(d >> 16)));
            res[i] = (__float_as_uint(lo) >> 16) | (__float_as_uint(hi) & 0xffff0000u);
        }
        if (cg == 0) {
            *(uint4*)(k_ws + (size_t)(b * 1024 + mg) * 8) = make_uint4(res[0], res[1], res[2], res[3]);
            v_t[((size_t)(b * 32 + 0) << 10) + mg] = (unsigned short)(res[4] & 0xffff);
            v_t[((size_t)(b * 32 + 1) << 10) + mg] = (unsigned short)(res[4] >> 16);
        } else {
            const int cvb = cg * 10 - 8;
#pragma unroll
            for (int i = 0; i < 5; ++i) {
                v_t[((size_t)(b * 32 + cvb + 2*i    ) << 10) + mg] = (unsigned short)(res[i] & 0xffff);
                v_t[((size_t)(b * 32 + cvb + 2*i + 1) << 10) + mg] = (unsigned short)(res[i] >> 16);
            }
        }
    }
}

// ---------------------------------------------------------------------------
// Kernel 2: flash attention core (R6 structure). ONE additive change:
// T14 async-STAGE split for V half 1 -- loads issued into registers BEFORE
// the first barrier (latency hides under phase-0 compute); only the LDS
// writes happen between the mid-kernel barriers. No indexing changes.
// ---------------------------------------------------------------------------
__global__ __launch_bounds__(256, 2) void attn_kernel(
    const unsigned short* __restrict__ q_ws, const unsigned short* __restrict__ k_ws,
    const unsigned short* __restrict__ v_t, unsigned short* __restrict__ o_ws)
{
    __shared__ __align__(16) char smem[49152];
    short* Klds = (short*)smem;     // [1024 rows][8 sh] permuted, 16KB
    char*  Vb   = smem + 16384;     // [32 cv][1024 B] half-V, XOR-swizzled, 32KB

    const int b = blockIdx.x >> 5, n0 = (blockIdx.x & 31) * 128;
    const int t = threadIdx.x;
    const int wid = t >> 6, lane = t & 63;
    const int l16 = lane & 15, g4 = lane >> 4;

    union { uint4 u4; short8 s8; } qfA, qfB;
    qfA.u4 = *(const uint4*)(q_ws + (size_t)(b * 4096 + n0 + wid * 32 + l16) * 8);
    qfB.u4 = *(const uint4*)(q_ws + (size_t)(b * 4096 + n0 + wid * 32 + 16 + l16) * 8);

    // K stage (whole batch), permuted rows
#pragma unroll
    for (int p = 0; p < 4; ++p) {
        const int mg = p * 256 + t;
        const uint4 kr = *(const uint4*)(k_ws + (size_t)(b * 1024 + mg) * 8);
        const int row = (mg & ~31) | (((mg >> 2) & 1) << 4) | (((mg >> 3) & 3) << 2) | (mg & 3);
        *(uint4*)&Klds[row * 8] = kr;
    }
    // V half staging: [cv][1024B] (512 m), swizzled by cv
    const int scv = t >> 3, sj8 = t & 7;
    const unsigned short* vsrc0 = v_t + ((size_t)b << 15) + scv * 1024;
    char* vdst = Vb + scv * 1024;
    const int vsw = (scv & 7) << 4;

    // phase-0 V -> LDS now
#pragma unroll
    for (int k = 0; k < 8; ++k) {
        const int off = (k * 8 + sj8) * 16;
        const uint4 vv = *(const uint4*)((const char*)vsrc0 + off);
        *(uint4*)(vdst + (off ^ vsw)) = vv;
    }
    // T14: issue phase-1 V loads into registers (latency hides under phase 0)
    uint4 pf[8];
#pragma unroll
    for (int k = 0; k < 8; ++k) {
        const int off = (k * 8 + sj8) * 16;
        pf[k] = *(const uint4*)((const char*)(vsrc0 + 512) + off);
    }

    f32x4 a0A = {0,0,0,0}, a1A = {0,0,0,0}, a0B = {0,0,0,0}, a1B = {0,0,0,0};
    float lA = 0.f, lB = 0.f;

    __syncthreads();

    const int rsw = (l16 & 7) << 4;
#pragma unroll
    for (int ph = 0; ph < 2; ++ph) {
        if (ph == 1) {
            __syncthreads();          // all phase-0 V reads done
#pragma unroll
            for (int k = 0; k < 8; ++k) {
                const int off = (k * 8 + sj8) * 16;
                *(uint4*)(vdst + (off ^ vsw)) = pf[k];   // write-late (loads long done)
            }
            __syncthreads();
        }
        for (int sl = 0; sl < 16; ++sl) {
            const int rb = ph * 512 + sl * 32;
            const short8 A0 = *(const short8*)&Klds[(rb + l16) * 8];
            const short8 A1 = *(const short8*)&Klds[(rb + 16 + l16) * 8];
            const f32x4 z = {0,0,0,0};
            const f32x4 sA0 = __builtin_amdgcn_mfma_f32_16x16x32_bf16(A0, qfA.s8, z, 0, 0, 0);
            const f32x4 sA1 = __builtin_amdgcn_mfma_f32_16x16x32_bf16(A1, qfA.s8, z, 0, 0, 0);
            const f32x4 sB0 = __builtin_amdgcn_mfma_f32_16x16x32_bf16(A0, qfB.s8, z, 0, 0, 0);
            const f32x4 sB1 = __builtin_amdgcn_mfma_f32_16x16x32_bf16(A1, qfB.s8, z, 0, 0, 0);

            float eA[8], eB[8];
            float psA = 0.f, psB = 0.f;
#pragma unroll
            for (int i = 0; i < 4; ++i) {
                eA[i]     = fast_exp2(sA0[i]); psA += eA[i];
                eA[4 + i] = fast_exp2(sA1[i]); psA += eA[4 + i];
                eB[i]     = fast_exp2(sB0[i]); psB += eB[i];
                eB[4 + i] = fast_exp2(sB1[i]); psB += eB[4 + i];
            }
            lA += psA; lB += psB;

            union { unsigned int u[4]; short8 s8; } pbA, pbB;
            pbA.u[0] = cvt_pk_bf16(eA[0], eA[1]); pbA.u[1] = cvt_pk_bf16(eA[2], eA[3]);
            pbA.u[2] = cvt_pk_bf16(eA[4], eA[5]); pbA.u[3] = cvt_pk_bf16(eA[6], eA[7]);
            pbB.u[0] = cvt_pk_bf16(eB[0], eB[1]); pbB.u[1] = cvt_pk_bf16(eB[2], eB[3]);
            pbB.u[2] = cvt_pk_bf16(eB[4], eB[5]); pbB.u[3] = cvt_pk_bf16(eB[6], eB[7]);

            const int loc = sl * 64 + g4 * 16;                        // byte in half-row
            const short8 va0 = *(const short8*)(Vb + l16 * 1024 + (loc ^ rsw));
            const short8 va1 = *(const short8*)(Vb + (l16 + 16) * 1024 + (loc ^ rsw));
            a0A = __builtin_amdgcn_mfma_f32_16x16x32_bf16(va0, pbA.s8, a0A, 0, 0, 0);
            a1A = __builtin_amdgcn_mfma_f32_16x16x32_bf16(va1, pbA.s8, a1A, 0, 0, 0);
            a0B = __builtin_amdgcn_mfma_f32_16x16x32_bf16(va0, pbB.s8, a0B, 0, 0, 0);
            a1B = __builtin_amdgcn_mfma_f32_16x16x32_bf16(va1, pbB.s8, a1B, 0, 0, 0);
        }
    }

    // denominators (sum partials over the 4 g4 lane-groups)
    {
        float l2 = lA + __shfl_xor(lA, 16); l2 += __shfl_xor(l2, 32);
        const float inv = 1.0f / l2;
        a0A *= inv; a1A *= inv;
        float l3 = lB + __shfl_xor(lB, 16); l3 += __shfl_xor(l3, 32);
        const float inv2 = 1.0f / l3;
        a0B *= inv2; a1B *= inv2;
    }

    // o bf16 [b][n][32 cv]
    {
        const int nA = n0 + wid * 32 + l16, nB = nA + 16;
        unsigned short* oa = o_ws + (size_t)(b * 4096 + nA) * 32;
        unsigned short* ob = o_ws + (size_t)(b * 4096 + nB) * 32;
        *(uint2*)(oa + g4 * 4)      = make_uint2(cvt_pk_bf16(a0A[0], a0A[1]), cvt_pk_bf16(a0A[2], a0A[3]));
        *(uint2*)(oa + 16 + g4 * 4) = make_uint2(cvt_pk_bf16(a1A[0], a1A[1]), cvt_pk_bf16(a1A[2], a1A[3]));
        *(uint2*)(ob + g4 * 4)      = make_uint2(cvt_pk_bf16(a0B[0], a0B[1]), cvt_pk_bf16(a0B[2], a0B[3]));
        *(uint2*)(ob + 16 + g4 * 4) = make_uint2(cvt_pk_bf16(a1B[0], a1B[1]), cvt_pk_bf16(a1B[2], a1B[3]));
    }
}

// ---------------------------------------------------------------------------
// Kernel 3: out = gamma*(Wo@o)+x (R6 verbatim, proven).
// ---------------------------------------------------------------------------
__global__ __launch_bounds__(256, 4) void wo_res_kernel(
    const unsigned short* __restrict__ o_ws, const float* __restrict__ Wo,
    const float* __restrict__ x, const float* __restrict__ gamma_p,
    float* __restrict__ out)
{
    __shared__ __align__(16) short osm[64][36];      // 64 n x 32 cv bf16, pitch 72B

    const int b = blockIdx.x >> 6, s = blockIdx.x & 63;
    const int n0 = s * 64;
    const int t = threadIdx.x;
    const int wid = t >> 6, lane = t & 63;
    const int l16 = lane & 15, g4 = lane >> 4;

    {
        const int n = t >> 2, q = t & 3;
        const uint4 ov = *(const uint4*)(o_ws + (size_t)(b * 4096 + n0 + n) * 32 + q * 8);
        *(uint4*)&osm[n][q * 8] = ov;
    }
    short8 wf[4];
#pragma unroll
    for (int ct = 0; ct < 4; ++ct) {
        const float* wr = Wo + (ct * 16 + l16) * 32 + g4 * 8;
        const float4 wa = *(const float4*)wr;
        const float4 wb = *(const float4*)(wr + 4);
        union { unsigned int u[4]; short8 s8; } uu;
        uu.u[0] = cvt_pk_bf16(wa.x, wa.y); uu.u[1] = cvt_pk_bf16(wa.z, wa.w);
        uu.u[2] = cvt_pk_bf16(wb.x, wb.y); uu.u[3] = cvt_pk_bf16(wb.z, wb.w);
        wf[ct] = uu.s8;
    }
    const float gv = gamma_p[0];
    __syncthreads();

    const int nn = wid * 16 + l16;
    const short8 bfr = *(const short8*)&osm[nn][g4 * 8];
    f32x4 acc[4];
    const f32x4 z = {0,0,0,0};
#pragma unroll
    for (int ct = 0; ct < 4; ++ct)
        acc[ct] = __builtin_amdgcn_mfma_f32_16x16x32_bf16(wf[ct], bfr, z, 0, 0, 0);

    const int ncol = n0 + wid * 16 + l16;
#pragma unroll
    for (int ct = 0; ct < 4; ++ct) {
#pragma unroll
        for (int i = 0; i < 4; ++i) {
            const int c = ct * 16 + g4 * 4 + i;
            const size_t gi = ((size_t)(b * 64 + c) << 12) + ncol;
            out[gi] = fmaf(gv, acc[ct][i], x[gi]);
        }
    }
}

// ---------------------------------------------------------------------------
extern "C" void kernel_launch(void* const* d_in, const int* in_sizes, int n_in,
                              void* d_out, int out_size, void* d_ws, size_t ws_size,
                              hipStream_t stream) {
    const float* x     = (const float*)d_in[0];
    const float* Wq    = (const float*)d_in[1];
    const float* Wk    = (const float*)d_in[2];
    const float* Wv    = (const float*)d_in[3];
    const float* Wo    = (const float*)d_in[4];
    const float* gamma = (const float*)d_in[5];
    float* out = (float*)d_out;

    char* ws = (char*)d_ws;
    unsigned short* q_ws = (unsigned short*)ws;                               // 1 MB
    unsigned short* k_ws = (unsigned short*)(ws + (1 << 20));                 // 256 KB
    unsigned short* v_t  = (unsigned short*)(ws + (1 << 20) + (256 << 10));   // 1 MB
    unsigned short* o_ws = (unsigned short*)(ws + (2 << 20) + (256 << 10));   // 4 MB

    proj_pool_kernel<<<dim3(512), dim3(256), 0, stream>>>(x, Wq, Wk, Wv, q_ws, k_ws, v_t);
    attn_kernel<<<dim3(512), dim3(256), 0, stream>>>(q_ws, k_ws, v_t, o_ws);
    wo_res_kernel<<<dim3(1024), dim3(256), 0, stream>>>(o_ws, Wo, x, gamma, out);
}

// Round 15
// 33.771 us; speedup vs baseline: 1.0806x; 1.0806x over previous
//
#include <hip/hip_runtime.h>
#include <hip/hip_bf16.h>

typedef __attribute__((ext_vector_type(8))) short short8;
typedef __attribute__((ext_vector_type(4))) float f32x4;

#define LOG2E 1.4426950408889634f

__device__ __forceinline__ float bf2f(unsigned short s) {
    return __uint_as_float((unsigned int)s << 16);
}
__device__ __forceinline__ float fast_exp2(float x) {
#if __has_builtin(__builtin_amdgcn_exp2f)
    return __builtin_amdgcn_exp2f(x);
#else
    return __expf(x * 0.6931471805599453f);
#endif
}
__device__ __forceinline__ unsigned int cvt_pk_bf16(float lo, float hi) {
    unsigned int r;
    asm("v_cvt_pk_bf16_f32 %0, %1, %2" : "=v"(r) : "v"(lo), "v"(hi));
    return r;
}

// ---------------------------------------------------------------------------
// Kernel 1: MFMA 1x1-conv projections + 2x2 maxpool (R6 verbatim, proven).
// W in register A-frags; x staged once to LDS as swizzled bf16 [n][c];
// q pre-scaled by log2e/4 (exp2-domain softmax + 4x-redundant K-dim).
// ---------------------------------------------------------------------------
__global__ __launch_bounds__(256, 2) void proj_pool_kernel(
    const float* __restrict__ x, const float* __restrict__ Wq,
    const float* __restrict__ Wk, const float* __restrict__ Wv,
    unsigned short* __restrict__ q_ws, unsigned short* __restrict__ k_ws,
    unsigned short* __restrict__ v_t)
{
    __shared__ __align__(16) char smem[28672];
    char* xT = smem;                                    // [128 n][128 B] bf16, swizzled
    unsigned int* kv = (unsigned int*)(smem + 16384);   // [128 n][24 u32] (40 bf16 ch)

    const int b = blockIdx.x >> 5, s = blockIdx.x & 31;
    const int n0 = s * 128;
    const int t = threadIdx.x;
    const int w = t >> 6, lane = t & 63;
    const int l16 = lane & 15, g4 = lane >> 4;

    short8 wf[3][2];
#pragma unroll
    for (int tile = 0; tile < 3; ++tile) {
        const float* wrow;
        float scale = 1.0f;
        if (tile == 0) {
            if (l16 < 8) { wrow = Wq + l16 * 64; scale = LOG2E * 0.25f; }
            else         { wrow = Wk + (l16 - 8) * 64; }
        } else if (tile == 1) wrow = Wv + l16 * 64;
        else                  wrow = Wv + (16 + l16) * 64;
#pragma unroll
        for (int ks = 0; ks < 2; ++ks) {
            const float4 wa = *(const float4*)(wrow + ks * 32 + g4 * 8);
            const float4 wb = *(const float4*)(wrow + ks * 32 + g4 * 8 + 4);
            union { unsigned int u[4]; short8 s8; } uu;
            uu.u[0] = cvt_pk_bf16(wa.x * scale, wa.y * scale);
            uu.u[1] = cvt_pk_bf16(wa.z * scale, wa.w * scale);
            uu.u[2] = cvt_pk_bf16(wb.x * scale, wb.y * scale);
            uu.u[3] = cvt_pk_bf16(wb.z * scale, wb.w * scale);
            wf[tile][ks] = uu.s8;
        }
    }

    {
        const int nloc = (w & 1) * 64 + lane;      // 0..127
        const int cbase = (w >> 1) * 32;
        const float* xp = x + (size_t)b * 262144 + (size_t)cbase * 4096 + n0 + nloc;
        unsigned int pk[16];
#pragma unroll
        for (int j = 0; j < 16; ++j) {
            const float e0 = xp[(size_t)(2 * j) * 4096];
            const float e1 = xp[(size_t)(2 * j + 1) * 4096];
            pk[j] = cvt_pk_bf16(e0, e1);
        }
        char* row = xT + nloc * 128;
        const int sw = (nloc & 7) << 4;
#pragma unroll
        for (int h = 0; h < 4; ++h) {
            const uint4 u = make_uint4(pk[h*4+0], pk[h*4+1], pk[h*4+2], pk[h*4+3]);
            *(uint4*)(row + ((((cbase >> 3) + h) * 16) ^ sw)) = u;
        }
    }
    __syncthreads();

#pragma unroll
    for (int p = 0; p < 2; ++p) {
        const int tile = w * 2 + p;
        const int nl = tile * 16 + l16;
        f32x4 C0 = {0,0,0,0}, C1 = {0,0,0,0}, C2 = {0,0,0,0};
#pragma unroll
        for (int ks = 0; ks < 2; ++ks) {
            const short8 xb = *(const short8*)(xT + nl * 128 + ((((ks*4+g4)*16)) ^ ((l16&7)<<4)));
            C0 = __builtin_amdgcn_mfma_f32_16x16x32_bf16(wf[0][ks], xb, C0, 0, 0, 0);
            C1 = __builtin_amdgcn_mfma_f32_16x16x32_bf16(wf[1][ks], xb, C1, 0, 0, 0);
            C2 = __builtin_amdgcn_mfma_f32_16x16x32_bf16(wf[2][ks], xb, C2, 0, 0, 0);
        }
        const unsigned int c0lo = cvt_pk_bf16(C0[0], C0[1]);
        const unsigned int c0hi = cvt_pk_bf16(C0[2], C0[3]);
        if (g4 < 2) {
            *(uint2*)(q_ws + (size_t)(b * 4096 + n0 + nl) * 8 + g4 * 4) = make_uint2(c0lo, c0hi);
        } else {
            *(uint2*)&kv[nl * 24 + (g4 - 2) * 2] = make_uint2(c0lo, c0hi);
        }
        *(uint2*)&kv[nl * 24 + 4 + g4 * 2] =
            make_uint2(cvt_pk_bf16(C1[0], C1[1]), cvt_pk_bf16(C1[2], C1[3]));
        *(uint2*)&kv[nl * 24 + 12 + g4 * 2] =
            make_uint2(cvt_pk_bf16(C2[0], C2[1]), cvt_pk_bf16(C2[2], C2[3]));
    }
    __syncthreads();

    if (t < 128) {
        const int m = t >> 2, cg = t & 3;
        const int r0 = m * 2, r2 = m * 2 + 64;
        const int mg = s * 32 + m;
        unsigned int res[5];
#pragma unroll
        for (int i = 0; i < 5; ++i) {
            const unsigned int a  = kv[(r0    ) * 24 + cg * 5 + i];
            const unsigned int b1 = kv[(r0 + 1) * 24 + cg * 5 + i];
            const unsigned int c  = kv[(r2    ) * 24 + cg * 5 + i];
            const unsigned int d  = kv[(r2 + 1) * 24 + cg * 5 + i];
            const float lo = fmaxf(fmaxf(bf2f(a & 0xffff), bf2f(b1 & 0xffff)),
                                   fmaxf(bf2f(c & 0xffff), bf2f(d & 0xffff)));
            const float hi = fmaxf(fmaxf(bf2f(a >> 16), bf2f(b1 >> 16)),
                                   fmaxf(bf2f(c >> 16), bf2f(d >> 16)));
            res[i] = (__float_as_uint(lo) >> 16) | (__float_as_uint(hi) & 0xffff0000u);
        }
        if (cg == 0) {
            *(uint4*)(k_ws + (size_t)(b * 1024 + mg) * 8) = make_uint4(res[0], res[1], res[2], res[3]);
            v_t[((size_t)(b * 32 + 0) << 10) + mg] = (unsigned short)(res[4] & 0xffff);
            v_t[((size_t)(b * 32 + 1) << 10) + mg] = (unsigned short)(res[4] >> 16);
        } else {
            const int cvb = cg * 10 - 8;
#pragma unroll
            for (int i = 0; i < 5; ++i) {
                v_t[((size_t)(b * 32 + cvb + 2*i    ) << 10) + mg] = (unsigned short)(res[i] & 0xffff);
                v_t[((size_t)(b * 32 + cvb + 2*i + 1) << 10) + mg] = (unsigned short)(res[i] >> 16);
            }
        }
    }
}

// ---------------------------------------------------------------------------
// Kernel 2: flash attention core (R6 verbatim, proven). Grid 512
// (16b x 32 n-tiles of 128) x 256 thr. K whole-batch in LDS (permuted rows,
// 16KB) + half-V (32KB, XOR-swizzled, 2-phase). Swapped-operand MFMA,
// no-max exp2 softmax (bounded scores), writes o bf16 [b][n][32cv].
// ---------------------------------------------------------------------------
__global__ __launch_bounds__(256, 2) void attn_kernel(
    const unsigned short* __restrict__ q_ws, const unsigned short* __restrict__ k_ws,
    const unsigned short* __restrict__ v_t, unsigned short* __restrict__ o_ws)
{
    __shared__ __align__(16) char smem[49152];
    short* Klds = (short*)smem;     // [1024 rows][8 sh] permuted, 16KB
    char*  Vb   = smem + 16384;     // [32 cv][1024 B] half-V, XOR-swizzled, 32KB

    const int b = blockIdx.x >> 5, n0 = (blockIdx.x & 31) * 128;
    const int t = threadIdx.x;
    const int wid = t >> 6, lane = t & 63;
    const int l16 = lane & 15, g4 = lane >> 4;

    union { uint4 u4; short8 s8; } qfA, qfB;
    qfA.u4 = *(const uint4*)(q_ws + (size_t)(b * 4096 + n0 + wid * 32 + l16) * 8);
    qfB.u4 = *(const uint4*)(q_ws + (size_t)(b * 4096 + n0 + wid * 32 + 16 + l16) * 8);

    // K stage (whole batch), permuted rows
#pragma unroll
    for (int p = 0; p < 4; ++p) {
        const int mg = p * 256 + t;
        const uint4 kr = *(const uint4*)(k_ws + (size_t)(b * 1024 + mg) * 8);
        const int row = (mg & ~31) | (((mg >> 2) & 1) << 4) | (((mg >> 3) & 3) << 2) | (mg & 3);
        *(uint4*)&Klds[row * 8] = kr;
    }
    // V half staging: [cv][1024B] (512 m), swizzled by cv
    const int scv = t >> 3, sj8 = t & 7;
    const unsigned short* vsrc0 = v_t + ((size_t)b << 15) + scv * 1024;
    char* vdst = Vb + scv * 1024;
    const int vsw = (scv & 7) << 4;
    auto stageVhalf = [&](int ph) {
#pragma unroll
        for (int k = 0; k < 8; ++k) {
            const int off = (k * 8 + sj8) * 16;                      // byte in half-row
            const uint4 vv = *(const uint4*)((const char*)(vsrc0 + ph * 512) + off);
            *(uint4*)(vdst + (off ^ vsw)) = vv;
        }
    };

    f32x4 a0A = {0,0,0,0}, a1A = {0,0,0,0}, a0B = {0,0,0,0}, a1B = {0,0,0,0};
    float lA = 0.f, lB = 0.f;

    stageVhalf(0);
    __syncthreads();

    const int rsw = (l16 & 7) << 4;
#pragma unroll
    for (int ph = 0; ph < 2; ++ph) {
        if (ph == 1) {
            __syncthreads();          // all phase-0 V reads done
            stageVhalf(1);
            __syncthreads();
        }
        for (int sl = 0; sl < 16; ++sl) {
            const int rb = ph * 512 + sl * 32;
            const short8 A0 = *(const short8*)&Klds[(rb + l16) * 8];
            const short8 A1 = *(const short8*)&Klds[(rb + 16 + l16) * 8];
            const f32x4 z = {0,0,0,0};
            const f32x4 sA0 = __builtin_amdgcn_mfma_f32_16x16x32_bf16(A0, qfA.s8, z, 0, 0, 0);
            const f32x4 sA1 = __builtin_amdgcn_mfma_f32_16x16x32_bf16(A1, qfA.s8, z, 0, 0, 0);
            const f32x4 sB0 = __builtin_amdgcn_mfma_f32_16x16x32_bf16(A0, qfB.s8, z, 0, 0, 0);
            const f32x4 sB1 = __builtin_amdgcn_mfma_f32_16x16x32_bf16(A1, qfB.s8, z, 0, 0, 0);

            float eA[8], eB[8];
            float psA = 0.f, psB = 0.f;
#pragma unroll
            for (int i = 0; i < 4; ++i) {
                eA[i]     = fast_exp2(sA0[i]); psA += eA[i];
                eA[4 + i] = fast_exp2(sA1[i]); psA += eA[4 + i];
                eB[i]     = fast_exp2(sB0[i]); psB += eB[i];
                eB[4 + i] = fast_exp2(sB1[i]); psB += eB[4 + i];
            }
            lA += psA; lB += psB;

            union { unsigned int u[4]; short8 s8; } pbA, pbB;
            pbA.u[0] = cvt_pk_bf16(eA[0], eA[1]); pbA.u[1] = cvt_pk_bf16(eA[2], eA[3]);
            pbA.u[2] = cvt_pk_bf16(eA[4], eA[5]); pbA.u[3] = cvt_pk_bf16(eA[6], eA[7]);
            pbB.u[0] = cvt_pk_bf16(eB[0], eB[1]); pbB.u[1] = cvt_pk_bf16(eB[2], eB[3]);
            pbB.u[2] = cvt_pk_bf16(eB[4], eB[5]); pbB.u[3] = cvt_pk_bf16(eB[6], eB[7]);

            const int loc = sl * 64 + g4 * 16;                        // byte in half-row
            const short8 va0 = *(const short8*)(Vb + l16 * 1024 + (loc ^ rsw));
            const short8 va1 = *(const short8*)(Vb + (l16 + 16) * 1024 + (loc ^ rsw));
            a0A = __builtin_amdgcn_mfma_f32_16x16x32_bf16(va0, pbA.s8, a0A, 0, 0, 0);
            a1A = __builtin_amdgcn_mfma_f32_16x16x32_bf16(va1, pbA.s8, a1A, 0, 0, 0);
            a0B = __builtin_amdgcn_mfma_f32_16x16x32_bf16(va0, pbB.s8, a0B, 0, 0, 0);
            a1B = __builtin_amdgcn_mfma_f32_16x16x32_bf16(va1, pbB.s8, a1B, 0, 0, 0);
        }
    }

    // denominators (sum partials over the 4 g4 lane-groups)
    {
        float l2 = lA + __shfl_xor(lA, 16); l2 += __shfl_xor(l2, 32);
        const float inv = 1.0f / l2;
        a0A *= inv; a1A *= inv;
        float l3 = lB + __shfl_xor(lB, 16); l3 += __shfl_xor(l3, 32);
        const float inv2 = 1.0f / l3;
        a0B *= inv2; a1B *= inv2;
    }

    // o bf16 [b][n][32 cv]
    {
        const int nA = n0 + wid * 32 + l16, nB = nA + 16;
        unsigned short* oa = o_ws + (size_t)(b * 4096 + nA) * 32;
        unsigned short* ob = o_ws + (size_t)(b * 4096 + nB) * 32;
        *(uint2*)(oa + g4 * 4)      = make_uint2(cvt_pk_bf16(a0A[0], a0A[1]), cvt_pk_bf16(a0A[2], a0A[3]));
        *(uint2*)(oa + 16 + g4 * 4) = make_uint2(cvt_pk_bf16(a1A[0], a1A[1]), cvt_pk_bf16(a1A[2], a1A[3]));
        *(uint2*)(ob + g4 * 4)      = make_uint2(cvt_pk_bf16(a0B[0], a0B[1]), cvt_pk_bf16(a0B[2], a0B[3]));
        *(uint2*)(ob + 16 + g4 * 4) = make_uint2(cvt_pk_bf16(a1B[0], a1B[1]), cvt_pk_bf16(a1B[2], a1B[3]));
    }
}

// ---------------------------------------------------------------------------
// Kernel 3: out = gamma*(Wo@o)+x (R6 verbatim, proven). Grid 1024 x 256 thr,
// tiny LDS -> high occupancy for the HBM stream; Wo A-frags from L2.
// ---------------------------------------------------------------------------
__global__ __launch_bounds__(256, 4) void wo_res_kernel(
    const unsigned short* __restrict__ o_ws, const float* __restrict__ Wo,
    const float* __restrict__ x, const float* __restrict__ gamma_p,
    float* __restrict__ out)
{
    __shared__ __align__(16) short osm[64][36];      // 64 n x 32 cv bf16, pitch 72B

    const int b = blockIdx.x >> 6, s = blockIdx.x & 63;
    const int n0 = s * 64;
    const int t = threadIdx.x;
    const int wid = t >> 6, lane = t & 63;
    const int l16 = lane & 15, g4 = lane >> 4;

    {
        const int n = t >> 2, q = t & 3;
        const uint4 ov = *(const uint4*)(o_ws + (size_t)(b * 4096 + n0 + n) * 32 + q * 8);
        *(uint4*)&osm[n][q * 8] = ov;
    }
    short8 wf[4];
#pragma unroll
    for (int ct = 0; ct < 4; ++ct) {
        const float* wr = Wo + (ct * 16 + l16) * 32 + g4 * 8;
        const float4 wa = *(const float4*)wr;
        const float4 wb = *(const float4*)(wr + 4);
        union { unsigned int u[4]; short8 s8; } uu;
        uu.u[0] = cvt_pk_bf16(wa.x, wa.y); uu.u[1] = cvt_pk_bf16(wa.z, wa.w);
        uu.u[2] = cvt_pk_bf16(wb.x, wb.y); uu.u[3] = cvt_pk_bf16(wb.z, wb.w);
        wf[ct] = uu.s8;
    }
    const float gv = gamma_p[0];
    __syncthreads();

    const int nn = wid * 16 + l16;
    const short8 bfr = *(const short8*)&osm[nn][g4 * 8];
    f32x4 acc[4];
    const f32x4 z = {0,0,0,0};
#pragma unroll
    for (int ct = 0; ct < 4; ++ct)
        acc[ct] = __builtin_amdgcn_mfma_f32_16x16x32_bf16(wf[ct], bfr, z, 0, 0, 0);

    const int ncol = n0 + wid * 16 + l16;
#pragma unroll
    for (int ct = 0; ct < 4; ++ct) {
#pragma unroll
        for (int i = 0; i < 4; ++i) {
            const int c = ct * 16 + g4 * 4 + i;
            const size_t gi = ((size_t)(b * 64 + c) << 12) + ncol;
            out[gi] = fmaf(gv, acc[ct][i], x[gi]);
        }
    }
}

// ---------------------------------------------------------------------------
extern "C" void kernel_launch(void* const* d_in, const int* in_sizes, int n_in,
                              void* d_out, int out_size, void* d_ws, size_t ws_size,
                              hipStream_t stream) {
    const float* x     = (const float*)d_in[0];
    const float* Wq    = (const float*)d_in[1];
    const float* Wk    = (const float*)d_in[2];
    const float* Wv    = (const float*)d_in[3];
    const float* Wo    = (const float*)d_in[4];
    const float* gamma = (const float*)d_in[5];
    float* out = (float*)d_out;

    char* ws = (char*)d_ws;
    unsigned short* q_ws = (unsigned short*)ws;                               // 1 MB
    unsigned short* k_ws = (unsigned short*)(ws + (1 << 20));                 // 256 KB
    unsigned short* v_t  = (unsigned short*)(ws + (1 << 20) + (256 << 10));   // 1 MB
    unsigned short* o_ws = (unsigned short*)(ws + (2 << 20) + (256 << 10));   // 4 MB

    proj_pool_kernel<<<dim3(512), dim3(256), 0, stream>>>(x, Wq, Wk, Wv, q_ws, k_ws, v_t);
    attn_kernel<<<dim3(512), dim3(256), 0, stream>>>(q_ws, k_ws, v_t, o_ws);
    wo_res_kernel<<<dim3(1024), dim3(256), 0, stream>>>(o_ws, Wo, x, gamma, out);
}